// Round 14
// baseline (993.528 us; speedup 1.0000x reference)
//
#include <hip/hip_runtime.h>

typedef unsigned short u16;
typedef unsigned int u32;
typedef __bf16 bf16x8 __attribute__((ext_vector_type(8)));
typedef float f32x4 __attribute__((ext_vector_type(4)));
typedef float f32x2 __attribute__((ext_vector_type(2)));

#define NN 50000
#define EE 600000
#define GG 256
#define LL 5
#define NB 196  // ceil(NN/256)

__device__ __forceinline__ float b2f(u16 u) {
  unsigned int v = ((unsigned int)u) << 16;
  return __builtin_bit_cast(float, v);
}
__device__ __forceinline__ u16 f2b(float f) {
  unsigned int u = __builtin_bit_cast(unsigned int, f);
  u += 0x7FFFu + ((u >> 16) & 1u);
  return (u16)(u >> 16);
}
// unpack bf16-pair u32 -> <2 x float> (enables v_pk_add_f32 / v_pk_max_f32)
__device__ __forceinline__ f32x2 up2(u32 v) {
  f32x2 r;
  r.x = __builtin_bit_cast(float, v << 16);
  r.y = __builtin_bit_cast(float, v & 0xFFFF0000u);
  return r;
}
__device__ __forceinline__ f32x2 max0(f32x2 v) {
  f32x2 r;
  r.x = fmaxf(v.x, 0.f);
  r.y = fmaxf(v.y, 0.f);
  return r;
}

// ---------- dtype detect: flag=1 means floating inputs are fp32 ----------
__global__ void k_detect(const u32* __restrict__ w, int* __restrict__ flag) {
  __shared__ int sh[256];
  u32 v = w[threadIdx.x];
  u32 lo = v & 0xFFFFu;
  u32 e = (lo >> 7) & 0xFFu;
  sh[threadIdx.x] = (e >= 0x60u && e <= 0x7Fu) ? 1 : 0;
  __syncthreads();
  for (int s = 128; s > 0; s >>= 1) {
    if (threadIdx.x < (unsigned)s) sh[threadIdx.x] += sh[threadIdx.x + s];
    __syncthreads();
  }
  if (threadIdx.x == 0) flag[0] = (sh[0] < 128) ? 1 : 0;
}

struct CvtArgs {
  const void* src[19];
  u16* dst[19];
  int cum[20];
};

__global__ void k_cvt_all(CvtArgs a, const int* __restrict__ flag) {
  int t = blockIdx.x * 256 + threadIdx.x;
  if (t >= a.cum[19]) return;
  int i = 0;
  while (t >= a.cum[i + 1]) ++i;
  int j = t - a.cum[i];
  if (flag[0]) a.dst[i][j] = f2b(((const float*)a.src[i])[j]);
  else a.dst[i][j] = ((const u16*)a.src[i])[j];
}

// ---------- tiled transpose: dst[n][k] = src[k][n], src is [K][N] ----------
__global__ void k_tr(const u16* __restrict__ src, u16* __restrict__ dst, int K, int N) {
  __shared__ u16 t[32][33];
  const int kb = blockIdx.x * 32, nb = blockIdx.y * 32;
  const int tx = threadIdx.x & 31, ty = threadIdx.x >> 5;
#pragma unroll
  for (int i = ty; i < 32; i += 8) t[i][tx] = src[(kb + i) * N + nb + tx];
  __syncthreads();
#pragma unroll
  for (int i = ty; i < 32; i += 8) dst[(nb + i) * K + kb + tx] = t[tx][i];
}

// ---------- fused init (also sets identity BN2 fold for layer-0 pull) ----------
__global__ void k_init(int* __restrict__ deg, float* __restrict__ rep,
                       float* __restrict__ bnbuf, int* __restrict__ gstart,
                       int* __restrict__ gend, float* __restrict__ c1b,
                       float* __restrict__ c0b) {
  int i = blockIdx.x * 256 + threadIdx.x;
  if (i < NN) deg[i] = 0;
  if (i < GG * 128) rep[i] = 0.f;
  if (i < 768) bnbuf[i] = 0.f;
  if (i < GG) { gstart[i] = 0; gend[i] = -1; }
  if (i < 128) { c1b[i] = 1.f; c0b[i] = 0.f; }
}

// ---------------- CSR build ----------------
__global__ void k_deg(const int* __restrict__ ei, int* __restrict__ deg) {
  int e = blockIdx.x * 256 + threadIdx.x;
  if (e < EE) atomicAdd(&deg[ei[EE + e]], 1);
}

__global__ void k_scan1(const int* __restrict__ deg, int* __restrict__ rowp,
                        int* __restrict__ bsum) {
  __shared__ int sh[256];
  int i = blockIdx.x * 256 + threadIdx.x;
  int v = (i < NN) ? deg[i] : 0;
  sh[threadIdx.x] = v;
  __syncthreads();
  for (int s = 1; s < 256; s <<= 1) {
    int t = (threadIdx.x >= (unsigned)s) ? sh[threadIdx.x - s] : 0;
    __syncthreads();
    sh[threadIdx.x] += t;
    __syncthreads();
  }
  if (i < NN) rowp[i] = sh[threadIdx.x] - v;
  if (threadIdx.x == 255) bsum[blockIdx.x] = sh[255];
}

__global__ void k_scan2(int* __restrict__ bsum, int* __restrict__ boff) {
  __shared__ int sh[256];
  int v = (threadIdx.x < NB) ? bsum[threadIdx.x] : 0;
  sh[threadIdx.x] = v;
  __syncthreads();
  for (int s = 1; s < 256; s <<= 1) {
    int t = (threadIdx.x >= (unsigned)s) ? sh[threadIdx.x - s] : 0;
    __syncthreads();
    sh[threadIdx.x] += t;
    __syncthreads();
  }
  if (threadIdx.x < NB) boff[threadIdx.x] = sh[threadIdx.x] - v;
}

__global__ void k_scan3(int* __restrict__ rowp, const int* __restrict__ boff,
                        int* __restrict__ cursor) {
  int i = blockIdx.x * 256 + threadIdx.x;
  if (i < NN) {
    int r = rowp[i] + boff[blockIdx.x];
    rowp[i] = r;
    cursor[i] = r;
  }
  if (i == 0) rowp[NN] = EE;
}

__global__ void k_fill(const int* __restrict__ ei, const int* __restrict__ eattr,
                       int* __restrict__ cursor, uint2* __restrict__ epack) {
  int e = blockIdx.x * 256 + threadIdx.x;
  if (e < EE) {
    int d = ei[EE + e];
    int pos = atomicAdd(&cursor[d], 1);
    u32 src = (u32)ei[e];
    u32 a0 = (u32)eattr[e * 3], a1 = (u32)eattr[e * 3 + 1], a2 = (u32)eattr[e * 3 + 2];
    epack[pos] = make_uint2(src | (a0 << 16) | (a1 << 23), a2);
  }
}

// ------- graph bounds: batch sorted -> boundary detection, no atomics -------
__global__ void k_gb(const int* __restrict__ batch, int* __restrict__ gstart,
                     int* __restrict__ gend) {
  int n = blockIdx.x * 256 + threadIdx.x;
  if (n >= NN) return;
  int b = batch[n];
  if (n == 0 || batch[n - 1] != b) gstart[b] = n;
  if (n == NN - 1 || batch[n + 1] != b) gend[b] = n;
}

// ---------------- atom embed (2 feats/thread) -> hpre ----------------
__global__ void k_atom(const int* __restrict__ x, const u16* __restrict__ aemb,
                       u16* __restrict__ hpre) {
  int idx = blockIdx.x * 256 + threadIdx.x;  // over NN*64
  if (idx >= NN * 64) return;
  int n = idx >> 6, f2 = (idx & 63) << 1;
  float a0 = 0.f, a1 = 0.f;
#pragma unroll
  for (int j = 0; j < 9; ++j) {
    int xv = x[n * 9 + j];
    u32 v = *(const u32*)(aemb + (j * 128 + xv) * 128 + f2);
    a0 += b2f((u16)v);
    a1 += b2f((u16)(v >> 16));
  }
  u32 o = (u32)f2b(a0) | ((u32)f2b(a1) << 16);
  *(u32*)(hpre + n * 128 + f2) = o;
}

// ------- pull v4: 2 edges/wave (half-wave each), 4 feats/lane (8B loads), BN2 fold on the fly -------
__global__ __launch_bounds__(256)
void k_pull(const u16* __restrict__ hpre, const float* __restrict__ cs1,
            const float* __restrict__ cs0, int relu_h, const int* __restrict__ rowp,
            const uint2* __restrict__ epack, const u16* __restrict__ bond,
            const u16* __restrict__ epsv, int layer, u16* __restrict__ amat) {
  const int lane = threadIdx.x & 63;
  const int half = lane >> 5;          // 0: even CSR slots, 1: odd slots
  const int node = blockIdx.x * 4 + (threadIdx.x >> 6);
  const int lo = (lane & 31) << 2;     // 4 features per lane
  const int p0 = rowp[node], p1 = rowp[node + 1];
  const u16* bondB = bond + 16384;
  const u16* bondC = bond + 32768;
  f32x2 c1L, c1H, c0L, c0H;
  c1L.x = cs1[lo];     c1L.y = cs1[lo + 1];
  c1H.x = cs1[lo + 2]; c1H.y = cs1[lo + 3];
  c0L.x = cs0[lo];     c0L.y = cs0[lo + 1];
  c0H.x = cs0[lo + 2]; c0H.y = cs0[lo + 3];
  auto actL = [&](u32 v) -> f32x2 {
    f32x2 t = up2(v) * c1L + c0L;
    if (relu_h) t = max0(t);
    return t;
  };
  auto actH = [&](u32 v) -> f32x2 {
    f32x2 t = up2(v) * c1H + c0H;
    if (relu_h) t = max0(t);
    return t;
  };
  f32x2 accL = {0.f, 0.f}, accH = {0.f, 0.f};
  int p = p0 + half;
  for (; p < p1 - 6; p += 8) {  // 4 edges per half per iteration (16 loads in flight)
    uint2 e0 = epack[p], e1 = epack[p + 2], e2 = epack[p + 4], e3 = epack[p + 6];
    uint2 hx0 = *(const uint2*)(hpre + (size_t)(e0.x & 0xFFFFu) * 128 + lo);
    uint2 hx1 = *(const uint2*)(hpre + (size_t)(e1.x & 0xFFFFu) * 128 + lo);
    uint2 hx2 = *(const uint2*)(hpre + (size_t)(e2.x & 0xFFFFu) * 128 + lo);
    uint2 hx3 = *(const uint2*)(hpre + (size_t)(e3.x & 0xFFFFu) * 128 + lo);
    uint2 ax0 = *(const uint2*)(bond + ((e0.x >> 16) & 0x7Fu) * 128 + lo);
    uint2 ax1 = *(const uint2*)(bond + ((e1.x >> 16) & 0x7Fu) * 128 + lo);
    uint2 ax2 = *(const uint2*)(bond + ((e2.x >> 16) & 0x7Fu) * 128 + lo);
    uint2 ax3 = *(const uint2*)(bond + ((e3.x >> 16) & 0x7Fu) * 128 + lo);
    uint2 bx0 = *(const uint2*)(bondB + ((e0.x >> 23) & 0x7Fu) * 128 + lo);
    uint2 bx1 = *(const uint2*)(bondB + ((e1.x >> 23) & 0x7Fu) * 128 + lo);
    uint2 bx2 = *(const uint2*)(bondB + ((e2.x >> 23) & 0x7Fu) * 128 + lo);
    uint2 bx3 = *(const uint2*)(bondB + ((e3.x >> 23) & 0x7Fu) * 128 + lo);
    uint2 cx0 = *(const uint2*)(bondC + e0.y * 128 + lo);
    uint2 cx1 = *(const uint2*)(bondC + e1.y * 128 + lo);
    uint2 cx2 = *(const uint2*)(bondC + e2.y * 128 + lo);
    uint2 cx3 = *(const uint2*)(bondC + e3.y * 128 + lo);
    accL += max0(actL(hx0.x) + up2(ax0.x) + up2(bx0.x) + up2(cx0.x));
    accH += max0(actH(hx0.y) + up2(ax0.y) + up2(bx0.y) + up2(cx0.y));
    accL += max0(actL(hx1.x) + up2(ax1.x) + up2(bx1.x) + up2(cx1.x));
    accH += max0(actH(hx1.y) + up2(ax1.y) + up2(bx1.y) + up2(cx1.y));
    accL += max0(actL(hx2.x) + up2(ax2.x) + up2(bx2.x) + up2(cx2.x));
    accH += max0(actH(hx2.y) + up2(ax2.y) + up2(bx2.y) + up2(cx2.y));
    accL += max0(actL(hx3.x) + up2(ax3.x) + up2(bx3.x) + up2(cx3.x));
    accH += max0(actH(hx3.y) + up2(ax3.y) + up2(bx3.y) + up2(cx3.y));
  }
  for (; p < p1; p += 2) {
    uint2 e0 = epack[p];
    uint2 hx0 = *(const uint2*)(hpre + (size_t)(e0.x & 0xFFFFu) * 128 + lo);
    uint2 ax0 = *(const uint2*)(bond + ((e0.x >> 16) & 0x7Fu) * 128 + lo);
    uint2 bx0 = *(const uint2*)(bondB + ((e0.x >> 23) & 0x7Fu) * 128 + lo);
    uint2 cx0 = *(const uint2*)(bondC + e0.y * 128 + lo);
    accL += max0(actL(hx0.x) + up2(ax0.x) + up2(bx0.x) + up2(cx0.x));
    accH += max0(actH(hx0.y) + up2(ax0.y) + up2(bx0.y) + up2(cx0.y));
  }
  // combine the two halves (lane i <-> lane i+32 hold the same 4 features)
  accL.x += __shfl_xor(accL.x, 32);
  accL.y += __shfl_xor(accL.y, 32);
  accH.x += __shfl_xor(accH.x, 32);
  accH.y += __shfl_xor(accH.y, 32);
  if (half == 0) {
    float epsf = 1.0f + b2f(epsv[layer]);
    uint2 own = *(const uint2*)(hpre + (size_t)node * 128 + lo);
    f32x2 oL = actL(own.x), oH = actH(own.y);
    u32 w0 = (u32)f2b(epsf * oL.x + accL.x) | ((u32)f2b(epsf * oL.y + accL.y) << 16);
    u32 w1 = (u32)f2b(epsf * oH.x + accH.x) | ((u32)f2b(epsf * oH.y + accH.y) << 16);
    *(uint2*)(amat + (size_t)node * 128 + lo) = make_uint2(w0, w1);
  }
}

// ---- GEMM1: z0 = amat @ W1 + b1 (bf16) + BN1 stats. Staging: hoisted loads, then LDS writes. ----
__global__ __launch_bounds__(256, 2)
void k_gemm1(const u16* __restrict__ amat, const u16* __restrict__ w1t,
             const u16* __restrict__ b1, u16* __restrict__ z0,
             float* __restrict__ bnsum, float* __restrict__ bnsq) {
  __shared__ u16 As[128 * 72];
  __shared__ u16 Bs[128 * 72];
  __shared__ float colAcc[256];
  const int tid = threadIdx.x;
  const int r0 = blockIdx.x * 128;
  const int nc = blockIdx.y * 128;
  const int w = tid >> 6, lane = tid & 63, l15 = lane & 15, q = lane >> 4;
  const int wr = (w & 1) * 64, wc = (w >> 1) * 64;
  const int srow = tid >> 3, sc8 = (tid & 7) << 3;
  f32x4 acc[4][4];
#pragma unroll
  for (int i = 0; i < 4; ++i)
#pragma unroll
    for (int j = 0; j < 4; ++j) acc[i][j] = {0.f, 0.f, 0.f, 0.f};

#pragma unroll
  for (int ks = 0; ks < 2; ++ks) {
    const int k0 = ks * 64;
    uint4 va[4], vb[4];
#pragma unroll
    for (int t = 0; t < 4; ++t) {
      const int row = srow + t * 32;
      int gr = r0 + row; if (gr >= NN) gr = NN - 1;
      va[t] = *(const uint4*)(amat + (size_t)gr * 128 + k0 + sc8);
      vb[t] = *(const uint4*)(w1t + (size_t)(nc + row) * 128 + k0 + sc8);
    }
#pragma unroll
    for (int t = 0; t < 4; ++t) {
      const int row = srow + t * 32;
      *(uint4*)(As + row * 72 + sc8) = va[t];
      *(uint4*)(Bs + row * 72 + sc8) = vb[t];
    }
    __syncthreads();
#pragma unroll
    for (int kk = 0; kk < 64; kk += 32) {
      const int kf = kk + q * 8;
      bf16x8 a[4], b[4];
#pragma unroll
      for (int i = 0; i < 4; ++i) a[i] = *(const bf16x8*)(As + (wr + i * 16 + l15) * 72 + kf);
#pragma unroll
      for (int j = 0; j < 4; ++j) b[j] = *(const bf16x8*)(Bs + (wc + j * 16 + l15) * 72 + kf);
#pragma unroll
      for (int i = 0; i < 4; ++i)
#pragma unroll
        for (int j = 0; j < 4; ++j)
          acc[i][j] = __builtin_amdgcn_mfma_f32_16x16x32_bf16(a[i], b[j], acc[i][j], 0, 0, 0);
    }
    __syncthreads();
  }
  colAcc[tid] = 0.f;
  __syncthreads();
#pragma unroll
  for (int j = 0; j < 4; ++j) {
    const int c = wc + j * 16 + l15;
    const float bias = b2f(b1[nc + c]);
    float ls = 0.f, lsq = 0.f;
#pragma unroll
    for (int i = 0; i < 4; ++i) {
      const int gr = r0 + wr + i * 16 + q * 4;
#pragma unroll
      for (int rg = 0; rg < 4; ++rg) {
        if (gr + rg < NN) {
          const float v = acc[i][j][rg] + bias;
          z0[(gr + rg) * 256 + nc + c] = f2b(v);
          ls += v;
          lsq += v * v;
        }
      }
    }
    atomicAdd(&colAcc[c], ls);
    atomicAdd(&colAcc[128 + c], lsq);
  }
  __syncthreads();
  if (tid < 128) {
    atomicAdd(&bnsum[nc + tid], colAcc[tid]);
    atomicAdd(&bnsq[nc + tid], colAcc[128 + tid]);
  }
}

// bnfin: reads stats, zeroes them, emits folded c1/c0
__global__ void k_bnfin(float* __restrict__ bnsum, float* __restrict__ bnsq,
                        const u16* __restrict__ g, const u16* __restrict__ b,
                        float* __restrict__ c1, float* __restrict__ c0) {
  int t = threadIdx.x;
  float s = bnsum[t], q = bnsq[t];
  bnsum[t] = 0.f;
  bnsq[t] = 0.f;
  float m = s * (1.0f / NN);
  float var = q * (1.0f / NN) - m * m;
  float rs = rsqrtf(var + 1e-5f);
  float cc1 = rs * b2f(g[t]);
  c1[t] = cc1;
  c0[t] = b2f(b[t]) - m * cc1;
}

// ---- GEMM2: hpre = relu(z0*c1+c0) @ W2 + b2 + BN2 stats. Staging: hoisted 16B loads + packed fold. ----
__global__ __launch_bounds__(256, 2)
void k_gemm2(const u16* __restrict__ z0, const float* __restrict__ c1,
             const float* __restrict__ c0, const u16* __restrict__ w2t,
             const u16* __restrict__ b2, u16* __restrict__ hpre,
             float* __restrict__ bnsum, float* __restrict__ bnsq) {
  __shared__ u16 As[128 * 72];
  __shared__ u16 Bs[128 * 72];
  __shared__ float colAcc[256];
  const int tid = threadIdx.x;
  const int r0 = blockIdx.x * 128;
  const int w = tid >> 6, lane = tid & 63, l15 = lane & 15, q = lane >> 4;
  const int wr = (w & 1) * 64, wc = (w >> 1) * 64;
  const int srow = tid >> 3, sc8 = (tid & 7) << 3;
  f32x4 acc[4][4];
#pragma unroll
  for (int i = 0; i < 4; ++i)
#pragma unroll
    for (int j = 0; j < 4; ++j) acc[i][j] = {0.f, 0.f, 0.f, 0.f};

#pragma unroll
  for (int ks = 0; ks < 4; ++ks) {
    const int k0 = ks * 64;
    const int kb = k0 + sc8;
    uint4 vz[4], vb[4];
#pragma unroll
    for (int t = 0; t < 4; ++t) {
      const int row = srow + t * 32;
      int gr = r0 + row; if (gr >= NN) gr = NN - 1;
      vz[t] = *(const uint4*)(z0 + (size_t)gr * 256 + kb);
      vb[t] = *(const uint4*)(w2t + (size_t)row * 256 + kb);
    }
    // fold coefficients for this thread's 8 k-columns
    f32x2 fc1[4], fc0[4];
#pragma unroll
    for (int e = 0; e < 4; ++e) {
      fc1[e].x = c1[kb + 2 * e];     fc1[e].y = c1[kb + 2 * e + 1];
      fc0[e].x = c0[kb + 2 * e];     fc0[e].y = c0[kb + 2 * e + 1];
    }
#pragma unroll
    for (int t = 0; t < 4; ++t) {
      const int row = srow + t * 32;
      u32 zw[4] = {vz[t].x, vz[t].y, vz[t].z, vz[t].w};
      u32 ow[4];
#pragma unroll
      for (int e = 0; e < 4; ++e) {
        f32x2 r = max0(up2(zw[e]) * fc1[e] + fc0[e]);
        ow[e] = (u32)f2b(r.x) | ((u32)f2b(r.y) << 16);
      }
      uint4 oz;
      oz.x = ow[0]; oz.y = ow[1]; oz.z = ow[2]; oz.w = ow[3];
      *(uint4*)(As + row * 72 + sc8) = oz;
      *(uint4*)(Bs + row * 72 + sc8) = vb[t];
    }
    __syncthreads();
#pragma unroll
    for (int kk = 0; kk < 64; kk += 32) {
      const int kf = kk + q * 8;
      bf16x8 a[4], b[4];
#pragma unroll
      for (int i = 0; i < 4; ++i) a[i] = *(const bf16x8*)(As + (wr + i * 16 + l15) * 72 + kf);
#pragma unroll
      for (int j = 0; j < 4; ++j) b[j] = *(const bf16x8*)(Bs + (wc + j * 16 + l15) * 72 + kf);
#pragma unroll
      for (int i = 0; i < 4; ++i)
#pragma unroll
        for (int j = 0; j < 4; ++j)
          acc[i][j] = __builtin_amdgcn_mfma_f32_16x16x32_bf16(a[i], b[j], acc[i][j], 0, 0, 0);
    }
    __syncthreads();
  }
  colAcc[tid] = 0.f;
  __syncthreads();
#pragma unroll
  for (int j = 0; j < 4; ++j) {
    const int c = wc + j * 16 + l15;
    const float bias = b2f(b2[c]);
    float ls = 0.f, lsq = 0.f;
#pragma unroll
    for (int i = 0; i < 4; ++i) {
      const int gr = r0 + wr + i * 16 + q * 4;
#pragma unroll
      for (int rg = 0; rg < 4; ++rg) {
        if (gr + rg < NN) {
          const float v = acc[i][j][rg] + bias;
          hpre[(gr + rg) * 128 + c] = f2b(v);
          ls += v;
          lsq += v * v;
        }
      }
    }
    atomicAdd(&colAcc[c], ls);
    atomicAdd(&colAcc[128 + c], lsq);
  }
  __syncthreads();
  if (tid < 128) {
    atomicAdd(&bnsum[tid], colAcc[tid]);
    atomicAdd(&bnsq[tid], colAcc[128 + tid]);
  }
}

// ------- segment pooling with on-the-fly BN2 fold: 4 blocks/graph, pre-reduced -------
__global__ void k_poolseg(const u16* __restrict__ hpre, const float* __restrict__ cs1,
                          const float* __restrict__ cs0, int dorelu,
                          const int* __restrict__ gstart, const int* __restrict__ gend,
                          float* __restrict__ rep) {
  int g = blockIdx.x >> 2, part = blockIdx.x & 3, f = threadIdx.x;  // 128 threads
  int r0 = gstart[g], r1 = gend[g] + 1;
  int len = r1 - r0;
  if (len <= 0) return;
  int chunk = (len + 3) >> 2;
  int s = r0 + part * chunk;
  int e = s + chunk; if (e > r1) e = r1;
  float cf1 = cs1[f], cf0 = cs0[f];
  float acc = 0.f;
  for (int r = s; r < e; ++r) {
    float v = b2f(hpre[r * 128 + f]) * cf1 + cf0;
    if (dorelu) v = fmaxf(v, 0.f);
    acc += v;
  }
  if (s < e) atomicAdd(&rep[g * 128 + f], acc);
}

// mean-divide; also emit bf16 copy for the MFMA FC head
__global__ void k_rep(float* __restrict__ rep, const int* __restrict__ gstart,
                      const int* __restrict__ gend, u16* __restrict__ repb) {
  int idx = blockIdx.x * 256 + threadIdx.x;  // GG*128
  int g = idx >> 7;
  int c = gend[g] - gstart[g] + 1;
  if (c < 1) c = 1;
  float v = rep[idx] / (float)c;
  rep[idx] = v;
  repb[idx] = f2b(v);
}

// ---- FC layer via MFMA: out[256][N] = relu(A[256][K] @ Wt[N][K]^T + bias) (bf16) ----
__global__ __launch_bounds__(256)
void k_fcg(const u16* __restrict__ A, const u16* __restrict__ Wt,
           const u16* __restrict__ bias, u16* __restrict__ out, int K, int N) {
  const int tid = threadIdx.x;
  const int r0 = blockIdx.x * 128;
  const int nc = blockIdx.y * 128;
  const int w = tid >> 6, lane = tid & 63, l15 = lane & 15, q = lane >> 4;
  const int wr = (w & 1) * 64, wc = (w >> 1) * 64;
  f32x4 acc[4][4];
#pragma unroll
  for (int i = 0; i < 4; ++i)
#pragma unroll
    for (int j = 0; j < 4; ++j) acc[i][j] = {0.f, 0.f, 0.f, 0.f};
  const int nkb = K >> 5;
  for (int kb = 0; kb < nkb; ++kb) {
    const int kf = kb * 32 + q * 8;
    bf16x8 a[4], b[4];
#pragma unroll
    for (int i = 0; i < 4; ++i)
      a[i] = *(const bf16x8*)(A + (size_t)(r0 + wr + i * 16 + l15) * K + kf);
#pragma unroll
    for (int j = 0; j < 4; ++j)
      b[j] = *(const bf16x8*)(Wt + (size_t)(nc + wc + j * 16 + l15) * K + kf);
#pragma unroll
    for (int i = 0; i < 4; ++i)
#pragma unroll
      for (int j = 0; j < 4; ++j)
        acc[i][j] = __builtin_amdgcn_mfma_f32_16x16x32_bf16(a[i], b[j], acc[i][j], 0, 0, 0);
  }
#pragma unroll
  for (int j = 0; j < 4; ++j) {
    const int c = nc + wc + j * 16 + l15;
    const float bv = b2f(bias[c]);
#pragma unroll
    for (int i = 0; i < 4; ++i) {
      const int gr = r0 + wr + i * 16 + q * 4;
#pragma unroll
      for (int rg = 0; rg < 4; ++rg)
        out[(gr + rg) * N + c] = f2b(fmaxf(acc[i][j][rg] + bv, 0.f));
    }
  }
}

__global__ void k_fc4(const u16* __restrict__ z, const u16* __restrict__ W,
                      const u16* __restrict__ bias, void* __restrict__ out,
                      const int* __restrict__ flag) {
  int g = blockIdx.x, lane = threadIdx.x;  // 64 threads
  float acc = 0.f;
  for (int k = lane; k < 512; k += 64) acc += b2f(z[g * 512 + k]) * b2f(W[k]);
  for (int off = 32; off > 0; off >>= 1) acc += __shfl_down(acc, off);
  if (lane == 0) {
    float r = acc + b2f(bias[0]);
    if (flag[0]) ((float*)out)[g] = r;
    else ((u16*)out)[g] = f2b(r);
  }
}

extern "C" void kernel_launch(void* const* d_in, const int* in_sizes, int n_in,
                              void* d_out, int out_size, void* d_ws, size_t ws_size,
                              hipStream_t stream) {
  const int* x     = (const int*)d_in[0];
  const int* ei    = (const int*)d_in[1];
  const int* eattr = (const int*)d_in[2];
  const int* batch = (const int*)d_in[3];

  char* ws = (char*)d_ws;
  size_t off = 0;
  auto alloc = [&](size_t bytes) -> void* {
    void* p = ws + off;
    off += (bytes + 255) & ~(size_t)255;
    return p;
  };
  int* flag = (int*)alloc(256);
  u16* cvt[23];
  CvtArgs ca;
  ca.cum[0] = 0;
  for (int i = 4; i <= 22; ++i) {
    cvt[i] = (u16*)alloc((size_t)in_sizes[i] * 2);
    ca.src[i - 4] = d_in[i];
    ca.dst[i - 4] = cvt[i];
    ca.cum[i - 3] = ca.cum[i - 4] + in_sizes[i];
  }

  u16*   hpre   = (u16*)  alloc((size_t)NN * 128 * 2);   // activations (pre-BN2)
  u16*   amat   = (u16*)  alloc((size_t)NN * 128 * 2);   // GEMM1 A
  u16*   z0     = (u16*)  alloc((size_t)NN * 256 * 2);
  u16*   w1t    = (u16*)  alloc(32768 * 2);
  u16*   w2t    = (u16*)  alloc(32768 * 2);
  u16*   ft1    = (u16*)  alloc((size_t)1024 * 128 * 2);
  u16*   ft2    = (u16*)  alloc((size_t)1024 * 1024 * 2);
  u16*   ft3    = (u16*)  alloc((size_t)512 * 1024 * 2);
  int*   deg    = (int*)  alloc((size_t)NN * 4);
  int*   cursor = (int*)  alloc((size_t)NN * 4);
  int*   rowp   = (int*)  alloc((size_t)(NN + 1) * 4);
  int*   bsum   = (int*)  alloc((size_t)NB * 4);
  int*   boff   = (int*)  alloc((size_t)NB * 4);
  uint2* epack  = (uint2*)alloc((size_t)EE * 8);
  float* bnbuf  = (float*)alloc(768 * 4);
  float* bnstat = (float*)alloc(768 * 4);
  float* rep    = (float*)alloc((size_t)GG * 128 * 4);
  u16*   repb   = (u16*)  alloc((size_t)GG * 128 * 2);
  int*   gstart = (int*)  alloc((size_t)GG * 4);
  int*   gend   = (int*)  alloc((size_t)GG * 4);
  u16*   fz1    = (u16*)  alloc((size_t)GG * 1024 * 2);
  u16*   fz2    = (u16*)  alloc((size_t)GG * 1024 * 2);
  u16*   fz3    = (u16*)  alloc((size_t)GG * 512 * 2);
  (void)ws_size; (void)n_in; (void)out_size;

  float* bn1sum = bnbuf;
  float* bn1sq  = bnbuf + 256;
  float* bn2sum = bnbuf + 512;
  float* bn2sq  = bnbuf + 640;
  float* c1a    = bnstat;          // BN1 folded scale (256)
  float* c0a    = bnstat + 256;    // BN1 folded shift (256)
  float* c1b    = bnstat + 512;    // BN2 folded scale (128) — identity at layer 0
  float* c0b    = bnstat + 640;    // BN2 folded shift (128)

  k_detect<<<1, 256, 0, stream>>>((const u32*)d_in[4], flag);
  {
    int total = ca.cum[19];
    k_cvt_all<<<(total + 255) / 256, 256, 0, stream>>>(ca, flag);
  }
  const u16 *aembc = cvt[4], *bembc = cvt[5], *epsc = cvt[6], *w1c = cvt[7],
            *b1c = cvt[8], *g1c = cvt[9], *be1c = cvt[10], *w2c = cvt[11],
            *b2c = cvt[12], *bngc = cvt[13], *bnbc = cvt[14], *fw1 = cvt[15],
            *fb1 = cvt[16], *fw2 = cvt[17], *fb2 = cvt[18], *fw3 = cvt[19],
            *fb3 = cvt[20], *fw4 = cvt[21], *fb4 = cvt[22];

  {
    dim3 t1(4, 8), t2(8, 4), t3(4, 32), t4(32, 32), t5(32, 16);
    k_tr<<<t1, 256, 0, stream>>>(w1c, w1t, 128, 256);
    k_tr<<<t2, 256, 0, stream>>>(w2c, w2t, 256, 128);
    k_tr<<<t3, 256, 0, stream>>>(fw1, ft1, 128, 1024);
    k_tr<<<t4, 256, 0, stream>>>(fw2, ft2, 1024, 1024);
    k_tr<<<t5, 256, 0, stream>>>(fw3, ft3, 1024, 512);
  }

  k_init<<<(NN + 255) / 256, 256, 0, stream>>>(deg, rep, bnbuf, gstart, gend, c1b, c0b);
  k_deg<<<(EE + 255) / 256, 256, 0, stream>>>(ei, deg);
  k_scan1<<<NB, 256, 0, stream>>>(deg, rowp, bsum);
  k_scan2<<<1, 256, 0, stream>>>(bsum, boff);
  k_scan3<<<NB, 256, 0, stream>>>(rowp, boff, cursor);
  k_fill<<<(EE + 255) / 256, 256, 0, stream>>>(ei, eattr, cursor, epack);
  k_gb<<<(NN + 255) / 256, 256, 0, stream>>>(batch, gstart, gend);
  k_atom<<<(NN * 64 + 255) / 256, 256, 0, stream>>>(x, aembc, hpre);
  // pool h0 (identity fold, no relu)
  k_poolseg<<<GG * 4, 128, 0, stream>>>(hpre, c1b, c0b, 0, gstart, gend, rep);

  const int gx = (NN + 127) / 128;  // 391
  for (int l = 0; l < LL; ++l) {
    k_pull<<<(NN + 3) / 4, 256, 0, stream>>>(hpre, c1b, c0b, (l > 0) ? 1 : 0, rowp, epack,
                                             bembc + (size_t)l * 3 * 128 * 128, epsc, l, amat);
    dim3 grid1(gx, 2);
    k_gemm1<<<grid1, 256, 0, stream>>>(amat, w1t, b1c, z0, bn1sum, bn1sq);
    k_bnfin<<<1, 256, 0, stream>>>(bn1sum, bn1sq, g1c, be1c, c1a, c0a);
    k_gemm2<<<gx, 256, 0, stream>>>(z0, c1a, c0a, w2t, b2c, hpre, bn2sum, bn2sq);
    k_bnfin<<<1, 128, 0, stream>>>(bn2sum, bn2sq, bngc + l * 128, bnbc + l * 128,
                                   c1b, c0b);
    k_poolseg<<<GG * 4, 128, 0, stream>>>(hpre, c1b, c0b, (l < LL - 1) ? 1 : 0,
                                          gstart, gend, rep);
  }

  k_rep<<<(GG * 128) / 256, 256, 0, stream>>>(rep, gstart, gend, repb);
  {
    dim3 g1(2, 8), g2(2, 8), g3(2, 4);
    k_fcg<<<g1, 256, 0, stream>>>(repb, ft1, fb1, fz1, 128, 1024);
    k_fcg<<<g2, 256, 0, stream>>>(fz1, ft2, fb2, fz2, 1024, 1024);
    k_fcg<<<g3, 256, 0, stream>>>(fz2, ft3, fb3, fz3, 1024, 512);
  }
  k_fc4<<<GG, 64, 0, stream>>>(fz3, fw4, fb4, d_out, flag);
}

// Round 15
// 859.451 us; speedup vs baseline: 1.1560x; 1.1560x over previous
//
#include <hip/hip_runtime.h>

typedef unsigned short u16;
typedef unsigned int u32;
typedef __bf16 bf16x8 __attribute__((ext_vector_type(8)));
typedef float f32x4 __attribute__((ext_vector_type(4)));
typedef float f32x2 __attribute__((ext_vector_type(2)));

#define NN 50000
#define EE 600000
#define GG 256
#define LL 5
#define NB 196  // ceil(NN/256)

__device__ __forceinline__ float b2f(u16 u) {
  unsigned int v = ((unsigned int)u) << 16;
  return __builtin_bit_cast(float, v);
}
__device__ __forceinline__ u16 f2b(float f) {
  unsigned int u = __builtin_bit_cast(unsigned int, f);
  u += 0x7FFFu + ((u >> 16) & 1u);
  return (u16)(u >> 16);
}
__device__ __forceinline__ f32x2 up2(u32 v) {
  f32x2 r;
  r.x = __builtin_bit_cast(float, v << 16);
  r.y = __builtin_bit_cast(float, v & 0xFFFF0000u);
  return r;
}
__device__ __forceinline__ f32x2 max0(f32x2 v) {
  f32x2 r;
  r.x = fmaxf(v.x, 0.f);
  r.y = fmaxf(v.y, 0.f);
  return r;
}

// ---------- dtype detect: flag=1 means floating inputs are fp32 ----------
__global__ void k_detect(const u32* __restrict__ w, int* __restrict__ flag) {
  __shared__ int sh[256];
  u32 v = w[threadIdx.x];
  u32 lo = v & 0xFFFFu;
  u32 e = (lo >> 7) & 0xFFu;
  sh[threadIdx.x] = (e >= 0x60u && e <= 0x7Fu) ? 1 : 0;
  __syncthreads();
  for (int s = 128; s > 0; s >>= 1) {
    if (threadIdx.x < (unsigned)s) sh[threadIdx.x] += sh[threadIdx.x + s];
    __syncthreads();
  }
  if (threadIdx.x == 0) flag[0] = (sh[0] < 128) ? 1 : 0;
}

struct CvtArgs {
  const void* src[19];
  u16* dst[19];
  int cum[20];
};

__global__ void k_cvt_all(CvtArgs a, const int* __restrict__ flag) {
  int t = blockIdx.x * 256 + threadIdx.x;
  if (t >= a.cum[19]) return;
  int i = 0;
  while (t >= a.cum[i + 1]) ++i;
  int j = t - a.cum[i];
  if (flag[0]) a.dst[i][j] = f2b(((const float*)a.src[i])[j]);
  else a.dst[i][j] = ((const u16*)a.src[i])[j];
}

// ---------- merged tiled transposes: one dispatch for all 5 weight matrices ----------
struct TrArgs {
  const u16* src[5];
  u16* dst[5];
  int K[5], N[5];
  int cum[6];  // cumulative 32x32 tile counts
};

__global__ void k_tr_all(TrArgs a) {
  __shared__ u16 t[32][33];
  int tile = blockIdx.x;
  int m = 0;
  while (tile >= a.cum[m + 1]) ++m;
  tile -= a.cum[m];
  const int K = a.K[m], N = a.N[m];
  const int ktiles = K >> 5;
  const int kb = (tile % ktiles) * 32, nb = (tile / ktiles) * 32;
  const u16* src = a.src[m];
  u16* dst = a.dst[m];
  const int tx = threadIdx.x & 31, ty = threadIdx.x >> 5;
#pragma unroll
  for (int i = ty; i < 32; i += 8) t[i][tx] = src[(kb + i) * N + nb + tx];
  __syncthreads();
#pragma unroll
  for (int i = ty; i < 32; i += 8) dst[(nb + i) * K + kb + tx] = t[tx][i];
}

// ---------- fused init (also sets identity BN2 fold for layer-0 pull) ----------
__global__ void k_init(int* __restrict__ deg, float* __restrict__ rep,
                       float* __restrict__ bnbuf, int* __restrict__ gstart,
                       int* __restrict__ gend, float* __restrict__ c1b,
                       float* __restrict__ c0b) {
  int i = blockIdx.x * 256 + threadIdx.x;
  if (i < NN) deg[i] = 0;
  if (i < GG * 128) rep[i] = 0.f;
  if (i < 768) bnbuf[i] = 0.f;
  if (i < GG) { gstart[i] = 0; gend[i] = -1; }
  if (i < 128) { c1b[i] = 1.f; c0b[i] = 0.f; }
}

// ---------------- CSR build ----------------
__global__ void k_deg(const int* __restrict__ ei, int* __restrict__ deg) {
  int e = blockIdx.x * 256 + threadIdx.x;
  if (e < EE) atomicAdd(&deg[ei[EE + e]], 1);
}

__global__ void k_scan1(const int* __restrict__ deg, int* __restrict__ rowp,
                        int* __restrict__ bsum) {
  __shared__ int sh[256];
  int i = blockIdx.x * 256 + threadIdx.x;
  int v = (i < NN) ? deg[i] : 0;
  sh[threadIdx.x] = v;
  __syncthreads();
  for (int s = 1; s < 256; s <<= 1) {
    int t = (threadIdx.x >= (unsigned)s) ? sh[threadIdx.x - s] : 0;
    __syncthreads();
    sh[threadIdx.x] += t;
    __syncthreads();
  }
  if (i < NN) rowp[i] = sh[threadIdx.x] - v;
  if (threadIdx.x == 255) bsum[blockIdx.x] = sh[255];
}

__global__ void k_scan2(int* __restrict__ bsum, int* __restrict__ boff) {
  __shared__ int sh[256];
  int v = (threadIdx.x < NB) ? bsum[threadIdx.x] : 0;
  sh[threadIdx.x] = v;
  __syncthreads();
  for (int s = 1; s < 256; s <<= 1) {
    int t = (threadIdx.x >= (unsigned)s) ? sh[threadIdx.x - s] : 0;
    __syncthreads();
    sh[threadIdx.x] += t;
    __syncthreads();
  }
  if (threadIdx.x < NB) boff[threadIdx.x] = sh[threadIdx.x] - v;
}

__global__ void k_scan3(int* __restrict__ rowp, const int* __restrict__ boff,
                        int* __restrict__ cursor) {
  int i = blockIdx.x * 256 + threadIdx.x;
  if (i < NN) {
    int r = rowp[i] + boff[blockIdx.x];
    rowp[i] = r;
    cursor[i] = r;
  }
  if (i == 0) rowp[NN] = EE;
}

__global__ void k_fill(const int* __restrict__ ei, const int* __restrict__ eattr,
                       int* __restrict__ cursor, uint2* __restrict__ epack) {
  int e = blockIdx.x * 256 + threadIdx.x;
  if (e < EE) {
    int d = ei[EE + e];
    int pos = atomicAdd(&cursor[d], 1);
    u32 src = (u32)ei[e];
    u32 a0 = (u32)eattr[e * 3], a1 = (u32)eattr[e * 3 + 1], a2 = (u32)eattr[e * 3 + 2];
    epack[pos] = make_uint2(src | (a0 << 16) | (a1 << 23), a2);
  }
}

// ------- graph bounds: batch sorted -> boundary detection, no atomics -------
__global__ void k_gb(const int* __restrict__ batch, int* __restrict__ gstart,
                     int* __restrict__ gend) {
  int n = blockIdx.x * 256 + threadIdx.x;
  if (n >= NN) return;
  int b = batch[n];
  if (n == 0 || batch[n - 1] != b) gstart[b] = n;
  if (n == NN - 1 || batch[n + 1] != b) gend[b] = n;
}

// ---------------- atom embed (2 feats/thread) -> hpre ----------------
__global__ void k_atom(const int* __restrict__ x, const u16* __restrict__ aemb,
                       u16* __restrict__ hpre) {
  int idx = blockIdx.x * 256 + threadIdx.x;  // over NN*64
  if (idx >= NN * 64) return;
  int n = idx >> 6, f2 = (idx & 63) << 1;
  float a0 = 0.f, a1 = 0.f;
#pragma unroll
  for (int j = 0; j < 9; ++j) {
    int xv = x[n * 9 + j];
    u32 v = *(const u32*)(aemb + (j * 128 + xv) * 128 + f2);
    a0 += b2f((u16)v);
    a1 += b2f((u16)(v >> 16));
  }
  u32 o = (u32)f2b(a0) | ((u32)f2b(a1) << 16);
  *(u32*)(hpre + n * 128 + f2) = o;
}

// ------- pull v3 (round-13 proven): wave/node, 2 feats/lane, 4-edge unroll, BN2 fold inline -------
__global__ __launch_bounds__(256)
void k_pull(const u16* __restrict__ hpre, const float* __restrict__ cs1,
            const float* __restrict__ cs0, int relu_h, const int* __restrict__ rowp,
            const uint2* __restrict__ epack, const u16* __restrict__ bond,
            const u16* __restrict__ epsv, int layer, u16* __restrict__ amat) {
  const int lane = threadIdx.x & 63;
  const int node = blockIdx.x * 4 + (threadIdx.x >> 6);
  const int p0 = rowp[node], p1 = rowp[node + 1];
  const int lo = lane << 1;
  const u16* bondB = bond + 16384;
  const u16* bondC = bond + 32768;
  f32x2 c1v, c0v;
  c1v.x = cs1[lo]; c1v.y = cs1[lo + 1];
  c0v.x = cs0[lo]; c0v.y = cs0[lo + 1];
  auto act = [&](u32 v) -> f32x2 {
    f32x2 t = up2(v) * c1v + c0v;
    if (relu_h) t = max0(t);
    return t;
  };
  f32x2 acc = {0.f, 0.f};
  int p = p0;
  for (; p + 4 <= p1; p += 4) {
    uint2 e0 = epack[p], e1 = epack[p + 1], e2 = epack[p + 2], e3 = epack[p + 3];
    u32 h0 = *(const u32*)(hpre + (size_t)(e0.x & 0xFFFFu) * 128 + lo);
    u32 h1 = *(const u32*)(hpre + (size_t)(e1.x & 0xFFFFu) * 128 + lo);
    u32 h2 = *(const u32*)(hpre + (size_t)(e2.x & 0xFFFFu) * 128 + lo);
    u32 h3 = *(const u32*)(hpre + (size_t)(e3.x & 0xFFFFu) * 128 + lo);
    u32 a0 = *(const u32*)(bond + ((e0.x >> 16) & 0x7Fu) * 128 + lo);
    u32 a1 = *(const u32*)(bond + ((e1.x >> 16) & 0x7Fu) * 128 + lo);
    u32 a2 = *(const u32*)(bond + ((e2.x >> 16) & 0x7Fu) * 128 + lo);
    u32 a3 = *(const u32*)(bond + ((e3.x >> 16) & 0x7Fu) * 128 + lo);
    u32 b0 = *(const u32*)(bondB + ((e0.x >> 23) & 0x7Fu) * 128 + lo);
    u32 b1 = *(const u32*)(bondB + ((e1.x >> 23) & 0x7Fu) * 128 + lo);
    u32 b2 = *(const u32*)(bondB + ((e2.x >> 23) & 0x7Fu) * 128 + lo);
    u32 b3 = *(const u32*)(bondB + ((e3.x >> 23) & 0x7Fu) * 128 + lo);
    u32 c0 = *(const u32*)(bondC + e0.y * 128 + lo);
    u32 c1 = *(const u32*)(bondC + e1.y * 128 + lo);
    u32 c2 = *(const u32*)(bondC + e2.y * 128 + lo);
    u32 c3 = *(const u32*)(bondC + e3.y * 128 + lo);
    acc += max0(act(h0) + up2(a0) + up2(b0) + up2(c0));
    acc += max0(act(h1) + up2(a1) + up2(b1) + up2(c1));
    acc += max0(act(h2) + up2(a2) + up2(b2) + up2(c2));
    acc += max0(act(h3) + up2(a3) + up2(b3) + up2(c3));
  }
  for (; p < p1; ++p) {
    uint2 e0 = epack[p];
    u32 h0 = *(const u32*)(hpre + (size_t)(e0.x & 0xFFFFu) * 128 + lo);
    u32 a0 = *(const u32*)(bond + ((e0.x >> 16) & 0x7Fu) * 128 + lo);
    u32 b0 = *(const u32*)(bondB + ((e0.x >> 23) & 0x7Fu) * 128 + lo);
    u32 c0 = *(const u32*)(bondC + e0.y * 128 + lo);
    acc += max0(act(h0) + up2(a0) + up2(b0) + up2(c0));
  }
  float epsf = 1.0f + b2f(epsv[layer]);
  u32 own = *(const u32*)(hpre + (size_t)node * 128 + lo);
  f32x2 ow = act(own);
  u32 o = (u32)f2b(epsf * ow.x + acc.x) | ((u32)f2b(epsf * ow.y + acc.y) << 16);
  *(u32*)(amat + (size_t)node * 128 + lo) = o;
}

// ---- GEMM1: z0 = amat @ W1 + b1 (bf16) + BN1 stats. Hoisted staging. ----
__global__ __launch_bounds__(256, 2)
void k_gemm1(const u16* __restrict__ amat, const u16* __restrict__ w1t,
             const u16* __restrict__ b1, u16* __restrict__ z0,
             float* __restrict__ bnsum, float* __restrict__ bnsq) {
  __shared__ u16 As[128 * 72];
  __shared__ u16 Bs[128 * 72];
  __shared__ float colAcc[256];
  const int tid = threadIdx.x;
  const int r0 = blockIdx.x * 128;
  const int nc = blockIdx.y * 128;
  const int w = tid >> 6, lane = tid & 63, l15 = lane & 15, q = lane >> 4;
  const int wr = (w & 1) * 64, wc = (w >> 1) * 64;
  const int srow = tid >> 3, sc8 = (tid & 7) << 3;
  f32x4 acc[4][4];
#pragma unroll
  for (int i = 0; i < 4; ++i)
#pragma unroll
    for (int j = 0; j < 4; ++j) acc[i][j] = {0.f, 0.f, 0.f, 0.f};

#pragma unroll
  for (int ks = 0; ks < 2; ++ks) {
    const int k0 = ks * 64;
    uint4 va[4], vb[4];
#pragma unroll
    for (int t = 0; t < 4; ++t) {
      const int row = srow + t * 32;
      int gr = r0 + row; if (gr >= NN) gr = NN - 1;
      va[t] = *(const uint4*)(amat + (size_t)gr * 128 + k0 + sc8);
      vb[t] = *(const uint4*)(w1t + (size_t)(nc + row) * 128 + k0 + sc8);
    }
#pragma unroll
    for (int t = 0; t < 4; ++t) {
      const int row = srow + t * 32;
      *(uint4*)(As + row * 72 + sc8) = va[t];
      *(uint4*)(Bs + row * 72 + sc8) = vb[t];
    }
    __syncthreads();
#pragma unroll
    for (int kk = 0; kk < 64; kk += 32) {
      const int kf = kk + q * 8;
      bf16x8 a[4], b[4];
#pragma unroll
      for (int i = 0; i < 4; ++i) a[i] = *(const bf16x8*)(As + (wr + i * 16 + l15) * 72 + kf);
#pragma unroll
      for (int j = 0; j < 4; ++j) b[j] = *(const bf16x8*)(Bs + (wc + j * 16 + l15) * 72 + kf);
#pragma unroll
      for (int i = 0; i < 4; ++i)
#pragma unroll
        for (int j = 0; j < 4; ++j)
          acc[i][j] = __builtin_amdgcn_mfma_f32_16x16x32_bf16(a[i], b[j], acc[i][j], 0, 0, 0);
    }
    __syncthreads();
  }
  colAcc[tid] = 0.f;
  __syncthreads();
#pragma unroll
  for (int j = 0; j < 4; ++j) {
    const int c = wc + j * 16 + l15;
    const float bias = b2f(b1[nc + c]);
    float ls = 0.f, lsq = 0.f;
#pragma unroll
    for (int i = 0; i < 4; ++i) {
      const int gr = r0 + wr + i * 16 + q * 4;
#pragma unroll
      for (int rg = 0; rg < 4; ++rg) {
        if (gr + rg < NN) {
          const float v = acc[i][j][rg] + bias;
          z0[(gr + rg) * 256 + nc + c] = f2b(v);
          ls += v;
          lsq += v * v;
        }
      }
    }
    atomicAdd(&colAcc[c], ls);
    atomicAdd(&colAcc[128 + c], lsq);
  }
  __syncthreads();
  if (tid < 128) {
    atomicAdd(&bnsum[nc + tid], colAcc[tid]);
    atomicAdd(&bnsq[nc + tid], colAcc[128 + tid]);
  }
}

// bnfin: reads stats, zeroes them, emits folded c1/c0
__global__ void k_bnfin(float* __restrict__ bnsum, float* __restrict__ bnsq,
                        const u16* __restrict__ g, const u16* __restrict__ b,
                        float* __restrict__ c1, float* __restrict__ c0) {
  int t = threadIdx.x;
  float s = bnsum[t], q = bnsq[t];
  bnsum[t] = 0.f;
  bnsq[t] = 0.f;
  float m = s * (1.0f / NN);
  float var = q * (1.0f / NN) - m * m;
  float rs = rsqrtf(var + 1e-5f);
  float cc1 = rs * b2f(g[t]);
  c1[t] = cc1;
  c0[t] = b2f(b[t]) - m * cc1;
}

// ---- GEMM2: hpre = relu(z0*c1+c0) @ W2 + b2 + BN2 stats. Hoisted 16B loads + packed fold. ----
__global__ __launch_bounds__(256, 2)
void k_gemm2(const u16* __restrict__ z0, const float* __restrict__ c1,
             const float* __restrict__ c0, const u16* __restrict__ w2t,
             const u16* __restrict__ b2, u16* __restrict__ hpre,
             float* __restrict__ bnsum, float* __restrict__ bnsq) {
  __shared__ u16 As[128 * 72];
  __shared__ u16 Bs[128 * 72];
  __shared__ float colAcc[256];
  const int tid = threadIdx.x;
  const int r0 = blockIdx.x * 128;
  const int w = tid >> 6, lane = tid & 63, l15 = lane & 15, q = lane >> 4;
  const int wr = (w & 1) * 64, wc = (w >> 1) * 64;
  const int srow = tid >> 3, sc8 = (tid & 7) << 3;
  f32x4 acc[4][4];
#pragma unroll
  for (int i = 0; i < 4; ++i)
#pragma unroll
    for (int j = 0; j < 4; ++j) acc[i][j] = {0.f, 0.f, 0.f, 0.f};

#pragma unroll
  for (int ks = 0; ks < 4; ++ks) {
    const int k0 = ks * 64;
    const int kb = k0 + sc8;
    uint4 vz[4], vb[4];
#pragma unroll
    for (int t = 0; t < 4; ++t) {
      const int row = srow + t * 32;
      int gr = r0 + row; if (gr >= NN) gr = NN - 1;
      vz[t] = *(const uint4*)(z0 + (size_t)gr * 256 + kb);
      vb[t] = *(const uint4*)(w2t + (size_t)row * 256 + kb);
    }
    f32x2 fc1[4], fc0[4];
#pragma unroll
    for (int e = 0; e < 4; ++e) {
      fc1[e].x = c1[kb + 2 * e];     fc1[e].y = c1[kb + 2 * e + 1];
      fc0[e].x = c0[kb + 2 * e];     fc0[e].y = c0[kb + 2 * e + 1];
    }
#pragma unroll
    for (int t = 0; t < 4; ++t) {
      const int row = srow + t * 32;
      u32 zw[4] = {vz[t].x, vz[t].y, vz[t].z, vz[t].w};
      u32 ow[4];
#pragma unroll
      for (int e = 0; e < 4; ++e) {
        f32x2 r = max0(up2(zw[e]) * fc1[e] + fc0[e]);
        ow[e] = (u32)f2b(r.x) | ((u32)f2b(r.y) << 16);
      }
      uint4 oz;
      oz.x = ow[0]; oz.y = ow[1]; oz.z = ow[2]; oz.w = ow[3];
      *(uint4*)(As + row * 72 + sc8) = oz;
      *(uint4*)(Bs + row * 72 + sc8) = vb[t];
    }
    __syncthreads();
#pragma unroll
    for (int kk = 0; kk < 64; kk += 32) {
      const int kf = kk + q * 8;
      bf16x8 a[4], b[4];
#pragma unroll
      for (int i = 0; i < 4; ++i) a[i] = *(const bf16x8*)(As + (wr + i * 16 + l15) * 72 + kf);
#pragma unroll
      for (int j = 0; j < 4; ++j) b[j] = *(const bf16x8*)(Bs + (wc + j * 16 + l15) * 72 + kf);
#pragma unroll
      for (int i = 0; i < 4; ++i)
#pragma unroll
        for (int j = 0; j < 4; ++j)
          acc[i][j] = __builtin_amdgcn_mfma_f32_16x16x32_bf16(a[i], b[j], acc[i][j], 0, 0, 0);
    }
    __syncthreads();
  }
  colAcc[tid] = 0.f;
  __syncthreads();
#pragma unroll
  for (int j = 0; j < 4; ++j) {
    const int c = wc + j * 16 + l15;
    const float bias = b2f(b2[c]);
    float ls = 0.f, lsq = 0.f;
#pragma unroll
    for (int i = 0; i < 4; ++i) {
      const int gr = r0 + wr + i * 16 + q * 4;
#pragma unroll
      for (int rg = 0; rg < 4; ++rg) {
        if (gr + rg < NN) {
          const float v = acc[i][j][rg] + bias;
          hpre[(gr + rg) * 128 + c] = f2b(v);
          ls += v;
          lsq += v * v;
        }
      }
    }
    atomicAdd(&colAcc[c], ls);
    atomicAdd(&colAcc[128 + c], lsq);
  }
  __syncthreads();
  if (tid < 128) {
    atomicAdd(&bnsum[tid], colAcc[tid]);
    atomicAdd(&bnsq[tid], colAcc[128 + tid]);
  }
}

// ------- segment pooling with BN2 fold: 8 blocks/graph, pre-reduced then one atomic -------
__global__ void k_poolseg(const u16* __restrict__ hpre, const float* __restrict__ cs1,
                          const float* __restrict__ cs0, int dorelu,
                          const int* __restrict__ gstart, const int* __restrict__ gend,
                          float* __restrict__ rep) {
  int g = blockIdx.x >> 3, part = blockIdx.x & 7, f = threadIdx.x;  // 128 threads
  int r0 = gstart[g], r1 = gend[g] + 1;
  int len = r1 - r0;
  if (len <= 0) return;
  int chunk = (len + 7) >> 3;
  int s = r0 + part * chunk;
  int e = s + chunk; if (e > r1) e = r1;
  if (s >= e) return;
  float cf1 = cs1[f], cf0 = cs0[f];
  float acc = 0.f;
  for (int r = s; r < e; ++r) {
    float v = b2f(hpre[r * 128 + f]) * cf1 + cf0;
    if (dorelu) v = fmaxf(v, 0.f);
    acc += v;
  }
  atomicAdd(&rep[g * 128 + f], acc);
}

// mean-divide; also emit bf16 copy for the MFMA FC head
__global__ void k_rep(float* __restrict__ rep, const int* __restrict__ gstart,
                      const int* __restrict__ gend, u16* __restrict__ repb) {
  int idx = blockIdx.x * 256 + threadIdx.x;  // GG*128
  int g = idx >> 7;
  int c = gend[g] - gstart[g] + 1;
  if (c < 1) c = 1;
  float v = rep[idx] / (float)c;
  rep[idx] = v;
  repb[idx] = f2b(v);
}

// ---- FC layer via MFMA: out[256][N] = relu(A[256][K] @ Wt[N][K]^T + bias) (bf16) ----
__global__ __launch_bounds__(256)
void k_fcg(const u16* __restrict__ A, const u16* __restrict__ Wt,
           const u16* __restrict__ bias, u16* __restrict__ out, int K, int N) {
  const int tid = threadIdx.x;
  const int r0 = blockIdx.x * 128;
  const int nc = blockIdx.y * 128;
  const int w = tid >> 6, lane = tid & 63, l15 = lane & 15, q = lane >> 4;
  const int wr = (w & 1) * 64, wc = (w >> 1) * 64;
  f32x4 acc[4][4];
#pragma unroll
  for (int i = 0; i < 4; ++i)
#pragma unroll
    for (int j = 0; j < 4; ++j) acc[i][j] = {0.f, 0.f, 0.f, 0.f};
  const int nkb = K >> 5;
  for (int kb = 0; kb < nkb; ++kb) {
    const int kf = kb * 32 + q * 8;
    bf16x8 a[4], b[4];
#pragma unroll
    for (int i = 0; i < 4; ++i)
      a[i] = *(const bf16x8*)(A + (size_t)(r0 + wr + i * 16 + l15) * K + kf);
#pragma unroll
    for (int j = 0; j < 4; ++j)
      b[j] = *(const bf16x8*)(Wt + (size_t)(nc + wc + j * 16 + l15) * K + kf);
#pragma unroll
    for (int i = 0; i < 4; ++i)
#pragma unroll
      for (int j = 0; j < 4; ++j)
        acc[i][j] = __builtin_amdgcn_mfma_f32_16x16x32_bf16(a[i], b[j], acc[i][j], 0, 0, 0);
  }
#pragma unroll
  for (int j = 0; j < 4; ++j) {
    const int c = nc + wc + j * 16 + l15;
    const float bv = b2f(bias[c]);
#pragma unroll
    for (int i = 0; i < 4; ++i) {
      const int gr = r0 + wr + i * 16 + q * 4;
#pragma unroll
      for (int rg = 0; rg < 4; ++rg)
        out[(gr + rg) * N + c] = f2b(fmaxf(acc[i][j][rg] + bv, 0.f));
    }
  }
}

__global__ void k_fc4(const u16* __restrict__ z, const u16* __restrict__ W,
                      const u16* __restrict__ bias, void* __restrict__ out,
                      const int* __restrict__ flag) {
  int g = blockIdx.x, lane = threadIdx.x;  // 64 threads
  float acc = 0.f;
  for (int k = lane; k < 512; k += 64) acc += b2f(z[g * 512 + k]) * b2f(W[k]);
  for (int off = 32; off > 0; off >>= 1) acc += __shfl_down(acc, off);
  if (lane == 0) {
    float r = acc + b2f(bias[0]);
    if (flag[0]) ((float*)out)[g] = r;
    else ((u16*)out)[g] = f2b(r);
  }
}

extern "C" void kernel_launch(void* const* d_in, const int* in_sizes, int n_in,
                              void* d_out, int out_size, void* d_ws, size_t ws_size,
                              hipStream_t stream) {
  const int* x     = (const int*)d_in[0];
  const int* ei    = (const int*)d_in[1];
  const int* eattr = (const int*)d_in[2];
  const int* batch = (const int*)d_in[3];

  char* ws = (char*)d_ws;
  size_t off = 0;
  auto alloc = [&](size_t bytes) -> void* {
    void* p = ws + off;
    off += (bytes + 255) & ~(size_t)255;
    return p;
  };
  int* flag = (int*)alloc(256);
  u16* cvt[23];
  CvtArgs ca;
  ca.cum[0] = 0;
  for (int i = 4; i <= 22; ++i) {
    cvt[i] = (u16*)alloc((size_t)in_sizes[i] * 2);
    ca.src[i - 4] = d_in[i];
    ca.dst[i - 4] = cvt[i];
    ca.cum[i - 3] = ca.cum[i - 4] + in_sizes[i];
  }

  u16*   hpre   = (u16*)  alloc((size_t)NN * 128 * 2);
  u16*   amat   = (u16*)  alloc((size_t)NN * 128 * 2);
  u16*   z0     = (u16*)  alloc((size_t)NN * 256 * 2);
  u16*   w1t    = (u16*)  alloc(32768 * 2);
  u16*   w2t    = (u16*)  alloc(32768 * 2);
  u16*   ft1    = (u16*)  alloc((size_t)1024 * 128 * 2);
  u16*   ft2    = (u16*)  alloc((size_t)1024 * 1024 * 2);
  u16*   ft3    = (u16*)  alloc((size_t)512 * 1024 * 2);
  int*   deg    = (int*)  alloc((size_t)NN * 4);
  int*   cursor = (int*)  alloc((size_t)NN * 4);
  int*   rowp   = (int*)  alloc((size_t)(NN + 1) * 4);
  int*   bsum   = (int*)  alloc((size_t)NB * 4);
  int*   boff   = (int*)  alloc((size_t)NB * 4);
  uint2* epack  = (uint2*)alloc((size_t)EE * 8);
  float* bnbuf  = (float*)alloc(768 * 4);
  float* bnstat = (float*)alloc(768 * 4);
  float* rep    = (float*)alloc((size_t)GG * 128 * 4);
  u16*   repb   = (u16*)  alloc((size_t)GG * 128 * 2);
  int*   gstart = (int*)  alloc((size_t)GG * 4);
  int*   gend   = (int*)  alloc((size_t)GG * 4);
  u16*   fz1    = (u16*)  alloc((size_t)GG * 1024 * 2);
  u16*   fz2    = (u16*)  alloc((size_t)GG * 1024 * 2);
  u16*   fz3    = (u16*)  alloc((size_t)GG * 512 * 2);
  (void)ws_size; (void)n_in; (void)out_size;

  float* bn1sum = bnbuf;
  float* bn1sq  = bnbuf + 256;
  float* bn2sum = bnbuf + 512;
  float* bn2sq  = bnbuf + 640;
  float* c1a    = bnstat;
  float* c0a    = bnstat + 256;
  float* c1b    = bnstat + 512;
  float* c0b    = bnstat + 640;

  k_detect<<<1, 256, 0, stream>>>((const u32*)d_in[4], flag);
  {
    int total = ca.cum[19];
    k_cvt_all<<<(total + 255) / 256, 256, 0, stream>>>(ca, flag);
  }
  const u16 *aembc = cvt[4], *bembc = cvt[5], *epsc = cvt[6], *w1c = cvt[7],
            *b1c = cvt[8], *g1c = cvt[9], *be1c = cvt[10], *w2c = cvt[11],
            *b2c = cvt[12], *bngc = cvt[13], *bnbc = cvt[14], *fw1 = cvt[15],
            *fb1 = cvt[16], *fw2 = cvt[17], *fb2 = cvt[18], *fw3 = cvt[19],
            *fb3 = cvt[20], *fw4 = cvt[21], *fb4 = cvt[22];

  {
    TrArgs ta;
    ta.src[0] = w1c; ta.dst[0] = w1t; ta.K[0] = 128;  ta.N[0] = 256;
    ta.src[1] = w2c; ta.dst[1] = w2t; ta.K[1] = 256;  ta.N[1] = 128;
    ta.src[2] = fw1; ta.dst[2] = ft1; ta.K[2] = 128;  ta.N[2] = 1024;
    ta.src[3] = fw2; ta.dst[3] = ft2; ta.K[3] = 1024; ta.N[3] = 1024;
    ta.src[4] = fw3; ta.dst[4] = ft3; ta.K[4] = 1024; ta.N[4] = 512;
    ta.cum[0] = 0;
    for (int m = 0; m < 5; ++m)
      ta.cum[m + 1] = ta.cum[m] + (ta.K[m] >> 5) * (ta.N[m] >> 5);
    k_tr_all<<<ta.cum[5], 256, 0, stream>>>(ta);
  }

  k_init<<<(NN + 255) / 256, 256, 0, stream>>>(deg, rep, bnbuf, gstart, gend, c1b, c0b);
  k_deg<<<(EE + 255) / 256, 256, 0, stream>>>(ei, deg);
  k_scan1<<<NB, 256, 0, stream>>>(deg, rowp, bsum);
  k_scan2<<<1, 256, 0, stream>>>(bsum, boff);
  k_scan3<<<NB, 256, 0, stream>>>(rowp, boff, cursor);
  k_fill<<<(EE + 255) / 256, 256, 0, stream>>>(ei, eattr, cursor, epack);
  k_gb<<<(NN + 255) / 256, 256, 0, stream>>>(batch, gstart, gend);
  k_atom<<<(NN * 64 + 255) / 256, 256, 0, stream>>>(x, aembc, hpre);
  // pool h0 (identity fold, no relu)
  k_poolseg<<<GG * 8, 128, 0, stream>>>(hpre, c1b, c0b, 0, gstart, gend, rep);

  const int gx = (NN + 127) / 128;  // 391
  for (int l = 0; l < LL; ++l) {
    k_pull<<<(NN + 3) / 4, 256, 0, stream>>>(hpre, c1b, c0b, (l > 0) ? 1 : 0, rowp, epack,
                                             bembc + (size_t)l * 3 * 128 * 128, epsc, l, amat);
    dim3 grid1(gx, 2);
    k_gemm1<<<grid1, 256, 0, stream>>>(amat, w1t, b1c, z0, bn1sum, bn1sq);
    k_bnfin<<<1, 256, 0, stream>>>(bn1sum, bn1sq, g1c, be1c, c1a, c0a);
    k_gemm2<<<gx, 256, 0, stream>>>(z0, c1a, c0a, w2t, b2c, hpre, bn2sum, bn2sq);
    k_bnfin<<<1, 128, 0, stream>>>(bn2sum, bn2sq, bngc + l * 128, bnbc + l * 128,
                                   c1b, c0b);
    k_poolseg<<<GG * 8, 128, 0, stream>>>(hpre, c1b, c0b, (l < LL - 1) ? 1 : 0,
                                          gstart, gend, rep);
  }

  k_rep<<<(GG * 128) / 256, 256, 0, stream>>>(rep, gstart, gend, repb);
  {
    dim3 g1(2, 8), g2(2, 8), g3(2, 4);
    k_fcg<<<g1, 256, 0, stream>>>(repb, ft1, fb1, fz1, 128, 1024);
    k_fcg<<<g2, 256, 0, stream>>>(fz1, ft2, fb2, fz2, 1024, 1024);
    k_fcg<<<g3, 256, 0, stream>>>(fz2, ft3, fb3, fz3, 1024, 512);
  }
  k_fc4<<<GG, 64, 0, stream>>>(fz3, fw4, fb4, d_out, flag);
}